// Round 8
// baseline (180.505 us; speedup 1.0000x reference)
//
#include <hip/hip_runtime.h>
#include <stdint.h>

#define NPTS   131072
#define DEMB   512
#define NCL    512
#define BM     128
#define NCHUNK 8
#define NTHREADS 512
#define NBLK   (NPTS / BM)          // 1024

typedef __attribute__((ext_vector_type(4))) float f32x4;
typedef __attribute__((ext_vector_type(8))) short short8;
typedef __attribute__((ext_vector_type(8))) unsigned short us8;

// ---- workspace layout (bytes) ----
// [0, 512KB)  : bf16 centroid fragments, per (chunk, wave, kk, n, lane):
//               each wave's (ch,kk,n) B-fragment is one contiguous 1KB wave-read.
// [512KB,+2KB): c2[k] = ||c_k||^2 (f32)
// [514KB,+8KB): per-block partial sums (f32)
#define WS_CB   0u
#define WS_C2   (512u * 1024u)
#define WS_PART (WS_C2 + 2048u)

static __device__ __forceinline__ unsigned short f2bf(float f) {
  union { float f; uint32_t u; } c{f};
  uint32_t r = c.u + 0x7FFFu + ((c.u >> 16) & 1u);   // round-to-nearest-even
  return (unsigned short)(r >> 16);
}

static __device__ __forceinline__ float sq4(f32x4 v) {
  return v[0] * v[0] + v[1] * v[1] + v[2] * v[2] + v[3] * v[3];
}

// ---- pinned-schedule load/wait primitives (volatile asm keeps program order) ----
#define LOAD_B8(DST, BASE)                                                     \
  do {                                                                         \
    const uint8_t* _b0 = (const uint8_t*)(BASE);                               \
    const uint8_t* _b1 = _b0 + 4096;                                           \
    asm volatile("global_load_dwordx4 %0, %8, off\n\t"                         \
                 "global_load_dwordx4 %1, %8, off offset:1024\n\t"             \
                 "global_load_dwordx4 %2, %8, off offset:2048\n\t"             \
                 "global_load_dwordx4 %3, %8, off offset:3072\n\t"             \
                 "global_load_dwordx4 %4, %9, off\n\t"                         \
                 "global_load_dwordx4 %5, %9, off offset:1024\n\t"             \
                 "global_load_dwordx4 %6, %9, off offset:2048\n\t"             \
                 "global_load_dwordx4 %7, %9, off offset:3072"                 \
                 : "=&v"(DST[0]), "=&v"(DST[1]), "=&v"(DST[2]), "=&v"(DST[3]), \
                   "=&v"(DST[4]), "=&v"(DST[5]), "=&v"(DST[6]), "=&v"(DST[7])  \
                 : "v"(_b0), "v"(_b1)                                          \
                 : "memory");                                                  \
  } while (0)

#define LOAD_E4(D, P)                                                          \
  asm volatile("global_load_dwordx4 %0, %4, off\n\t"                           \
               "global_load_dwordx4 %1, %4, off offset:16\n\t"                 \
               "global_load_dwordx4 %2, %4, off offset:32\n\t"                 \
               "global_load_dwordx4 %3, %4, off offset:48"                     \
               : "=&v"(D[0]), "=&v"(D[1]), "=&v"(D[2]), "=&v"(D[3])            \
               : "v"(P)                                                        \
               : "memory")

#define WAITV(N)                                                               \
  do {                                                                         \
    asm volatile("s_waitcnt vmcnt(" #N ")" ::: "memory");                      \
    __builtin_amdgcn_sched_barrier(0);                                         \
  } while (0)

#define BAR()                                                                  \
  do {                                                                         \
    asm volatile("s_waitcnt lgkmcnt(0)" ::: "memory");                         \
    __builtin_amdgcn_s_barrier();                                              \
  } while (0)

// ---------- prep: c2 + bf16 centroid fragments in register-load layout ----------
__global__ __launch_bounds__(128) void prep_kernel(const float* __restrict__ cent,
                                                   uint8_t* __restrict__ ws) {
  const int k = blockIdx.x;
  const int t = threadIdx.x;
  float4 v = ((const float4*)(cent + (size_t)k * DEMB))[t];
  float sq = v.x * v.x + v.y * v.y + v.z * v.z + v.w * v.w;
#pragma unroll
  for (int m = 1; m < 64; m <<= 1) sq += __shfl_xor(sq, m, 64);
  __shared__ float red[2];
  if ((t & 63) == 0) red[t >> 6] = sq;
  __syncthreads();
  if (t == 0) ((float*)(ws + WS_C2))[k] = red[0] + red[1];

  ushort4 b;
  b.x = f2bf(v.x); b.y = f2bf(v.y); b.z = f2bf(v.z); b.w = f2bf(v.w);
  const int d = t * 4;
  const int ch = d >> 6;
  const int dd = d & 63;
  const int slot = dd >> 3;            // 0..7
  const int kk = slot >> 2;            // 0..1
  const int lhi = slot & 3;            // 0..3
  const int w = k >> 6;
  const int kc = k & 63;
  const int n = kc >> 4;
  const int l15 = kc & 15;
  const int lane = lhi * 16 + l15;
  const uint32_t off =
      ((((uint32_t)(ch * 8 + w) * 2u + (uint32_t)kk) * 4u + (uint32_t)n) * 64u +
       (uint32_t)lane) * 16u + (uint32_t)(dd & 7) * 2u;
  *(ushort4*)(ws + WS_CB + off) = b;
}

// ---------- fused GEMM + softmin epilogue: BM=128, depth-2 E, 2-phase body ----------
__global__ __launch_bounds__(NTHREADS, 2) void main_kernel(
    const float* __restrict__ emb, const uint8_t* __restrict__ ws,
    const float* __restrict__ alphap) {
  __shared__ uint8_t Ab[2][16384];     // A tile dbuf [128 rows][64 d] bf16, XOR-swizzled
  __shared__ float redmin[1024];       // [8 waves][128 rows]
  __shared__ float redse[1024];
  __shared__ float redsge[1024];
  __shared__ float gmin[128];
  __shared__ float x2s[128];

  const int t = threadIdx.x;
  const int w = t >> 6;                // wave 0..7 -> clusters [64w, 64w+64)
  const int l = t & 63;
  const int l15 = l & 15;
  const int lhi = l >> 4;              // 0..3
  const int bid = blockIdx.x;
  const size_t row0 = (size_t)bid * BM;

  float* partials = (float*)(ws + WS_PART);

  f32x4 acc[8][4];
#pragma unroll
  for (int m = 0; m < 8; ++m)
#pragma unroll
    for (int n = 0; n < 4; ++n) acc[m][n] = (f32x4){0.f, 0.f, 0.f, 0.f};

  // x staging: thread owns 64B of one row: row r = t>>2, float cols [q*16, q*16+16)
  const int r = t >> 2;
  const int q = t & 3;
  const float* xge = emb + (row0 + r) * DEMB + q * 16;
  uint32_t xoff16[2];
#pragma unroll
  for (int i = 0; i < 2; ++i)
    xoff16[i] = (uint32_t)r * 128u + (uint32_t)(((2 * q + i) ^ (r & 7)) << 4);

  float x2a = 0.f;

  // per-wave B fragment base: lane l's 16B; frag (ch,kk,n) at + ch*64KB + (kk*4+n)*1KB
  const uint8_t* fb = ws + WS_CB + (uint32_t)w * 8192u + (uint32_t)l * 16u;

  short8 bA[8], bB[8];
  f32x4 ev0[4], ev1[4];

#define STAGE_FROM(EV, DSTBUF)                                                 \
  do {                                                                         \
    uint8_t* _an = (DSTBUF);                                                   \
    _Pragma("unroll")                                                          \
    for (int i = 0; i < 2; ++i) {                                              \
      x2a += sq4(EV[2 * i]) + sq4(EV[2 * i + 1]);                              \
      us8 u;                                                                   \
      u[0] = f2bf(EV[2 * i][0]); u[1] = f2bf(EV[2 * i][1]);                    \
      u[2] = f2bf(EV[2 * i][2]); u[3] = f2bf(EV[2 * i][3]);                    \
      u[4] = f2bf(EV[2 * i + 1][0]); u[5] = f2bf(EV[2 * i + 1][1]);            \
      u[6] = f2bf(EV[2 * i + 1][2]); u[7] = f2bf(EV[2 * i + 1][3]);            \
      *(us8*)(_an + xoff16[i]) = u;                                            \
    }                                                                          \
  } while (0)

  // ---- prologue: E[0]->ev0, E[1]->ev1, B[0]->bA; wait E[0]; stage A[0] ----
  LOAD_E4(ev0, xge);
  LOAD_E4(ev1, xge + 64);
  LOAD_B8(bA, fb);
  WAITV(12);                           // E[0] landed; E[1]+B[0] in flight
  STAGE_FROM(ev0, &Ab[0][0]);
  BAR();

// Body ch: issue E[ch+2] -> ev[ch&1], B[ch+1] -> BNEXT; single WAITV retires
// B[cur] (+E[ch+1]); phase A (mh=0: 8 ds_reads, 32 MFMA); stage A[ch+1] from
// ev[(ch+1)&1] (already landed, no wait); phase B (mh=1); BAR.
// vmcnt ledger (queue oldest->newest at wait):
//   bodies 0-5: E[ch+1](4), B[ch](8), E[ch+2](4), B[ch+1](8) -> WAITV(12)
//   body 6:     E[7](4),   B[6](8),  B[7](8)               -> WAITV(8)
//   body 7:     B[7](8)                                     -> WAITV(0)
#define CHUNK_BODY(CH, BCUR, BNEXT, EVN, EVS, VN)                              \
  {                                                                            \
    if ((CH) + 2 < NCHUNK)                                                     \
      LOAD_E4(EVN, xge + ((CH) + 2) * 64);                                     \
    if ((CH) + 1 < NCHUNK)                                                     \
      LOAD_B8(BNEXT, fb + (uint32_t)((CH) + 1) * 65536u);                      \
    const uint8_t* xb = &Ab[(CH) & 1][0];                                      \
    WAITV(VN);                                                                 \
    /* phase A: mh = 0 */                                                      \
    {                                                                          \
      short8 af[2][4];                                                         \
      _Pragma("unroll")                                                        \
      for (int kk = 0; kk < 2; ++kk) {                                         \
        const int slot = kk * 4 + lhi;                                         \
        const uint32_t fo =                                                    \
            (uint32_t)l15 * 128u + (uint32_t)((slot ^ (l15 & 7)) << 4);        \
        _Pragma("unroll")                                                      \
        for (int mm = 0; mm < 4; ++mm)                                         \
          af[kk][mm] = *(const short8*)(xb + fo + (uint32_t)mm * 2048u);       \
      }                                                                        \
      __builtin_amdgcn_s_setprio(1);                                           \
      _Pragma("unroll")                                                        \
      for (int kk = 0; kk < 2; ++kk)                                           \
        _Pragma("unroll")                                                      \
        for (int mm = 0; mm < 4; ++mm)                                         \
          _Pragma("unroll")                                                    \
          for (int n = 0; n < 4; ++n)                                          \
            acc[mm][n] = __builtin_amdgcn_mfma_f32_16x16x32_bf16(              \
                af[kk][mm], BCUR[kk * 4 + n], acc[mm][n], 0, 0, 0);            \
      __builtin_amdgcn_s_setprio(0);                                           \
    }                                                                          \
    /* stage A[ch+1] (ev already landed) -- overlaps other waves' MFMAs */     \
    if ((CH) + 1 < NCHUNK)                                                     \
      STAGE_FROM(EVS, &Ab[((CH) + 1) & 1][0]);                                 \
    /* phase B: mh = 1 */                                                      \
    {                                                                          \
      short8 af[2][4];                                                         \
      _Pragma("unroll")                                                        \
      for (int kk = 0; kk < 2; ++kk) {                                         \
        const int slot = kk * 4 + lhi;                                         \
        const uint32_t fo =                                                    \
            (uint32_t)l15 * 128u + (uint32_t)((slot ^ (l15 & 7)) << 4);        \
        _Pragma("unroll")                                                      \
        for (int mm = 0; mm < 4; ++mm)                                         \
          af[kk][mm] =                                                         \
              *(const short8*)(xb + fo + (uint32_t)(4 + mm) * 2048u);          \
      }                                                                        \
      __builtin_amdgcn_s_setprio(1);                                           \
      _Pragma("unroll")                                                        \
      for (int kk = 0; kk < 2; ++kk)                                           \
        _Pragma("unroll")                                                      \
        for (int mm = 0; mm < 4; ++mm)                                         \
          _Pragma("unroll")                                                    \
          for (int n = 0; n < 4; ++n)                                          \
            acc[4 + mm][n] = __builtin_amdgcn_mfma_f32_16x16x32_bf16(          \
                af[kk][mm], BCUR[kk * 4 + n], acc[4 + mm][n], 0, 0, 0);        \
      __builtin_amdgcn_s_setprio(0);                                           \
    }                                                                          \
    BAR();                                                                     \
  }

  CHUNK_BODY(0, bA, bB, ev0, ev1, 12)
  CHUNK_BODY(1, bB, bA, ev1, ev0, 12)
  CHUNK_BODY(2, bA, bB, ev0, ev1, 12)
  CHUNK_BODY(3, bB, bA, ev1, ev0, 12)
  CHUNK_BODY(4, bA, bB, ev0, ev1, 12)
  CHUNK_BODY(5, bB, bA, ev1, ev0, 12)
  CHUNK_BODY(6, bA, bB, ev0, ev1, 8)
  CHUNK_BODY(7, bB, bA, ev1, ev0, 0)
#undef CHUNK_BODY
#undef STAGE_FROM

  // ---- epilogue: g = c2 - 2*s ; val_row = min + sum((g-M)e)/sum(e) + x2 ----
  const float alpha = alphap[0];
  float c2r[4];
  {
    const float* c2p = (const float*)(ws + WS_C2) + w * 64 + l15;
    asm volatile("global_load_dword %0, %4, off\n\t"
                 "global_load_dword %1, %4, off offset:64\n\t"
                 "global_load_dword %2, %4, off offset:128\n\t"
                 "global_load_dword %3, %4, off offset:192"
                 : "=&v"(c2r[0]), "=&v"(c2r[1]), "=&v"(c2r[2]), "=&v"(c2r[3])
                 : "v"(c2p)
                 : "memory");
    asm volatile("s_waitcnt vmcnt(0)" ::: "memory");
    __builtin_amdgcn_sched_barrier(0);
  }

  // per-row x2: 4 threads per row (lanes 4k..4k+3)
  x2a += __shfl_xor(x2a, 1, 64);
  x2a += __shfl_xor(x2a, 2, 64);
  if ((l & 3) == 0) x2s[r] = x2a;     // one writer per row

  float rmin[8][4];
#pragma unroll
  for (int m = 0; m < 8; ++m)
#pragma unroll
    for (int i = 0; i < 4; ++i) {
      float mn = c2r[0] - 2.f * acc[m][0][i];
#pragma unroll
      for (int n = 1; n < 4; ++n) mn = fminf(mn, c2r[n] - 2.f * acc[m][n][i]);
      rmin[m][i] = mn;
    }
#pragma unroll
  for (int msk = 1; msk < 16; msk <<= 1)
#pragma unroll
    for (int m = 0; m < 8; ++m)
#pragma unroll
      for (int i = 0; i < 4; ++i)
        rmin[m][i] = fminf(rmin[m][i], __shfl_xor(rmin[m][i], msk, 64));
  if (l15 == 0) {
#pragma unroll
    for (int m = 0; m < 8; ++m)
#pragma unroll
      for (int i = 0; i < 4; ++i)
        redmin[w * 128 + m * 16 + lhi * 4 + i] = rmin[m][i];
  }
  __syncthreads();
  if (t < 128) {
    float mn = redmin[t];
#pragma unroll
    for (int w2 = 1; w2 < 8; ++w2) mn = fminf(mn, redmin[w2 * 128 + t]);
    gmin[t] = mn;
  }
  __syncthreads();
#pragma unroll
  for (int m = 0; m < 8; ++m) {
#pragma unroll
    for (int i = 0; i < 4; ++i) {
      const int row = m * 16 + lhi * 4 + i;
      const float M = gmin[row];
      float se = 0.f, sge = 0.f;
#pragma unroll
      for (int n = 0; n < 4; ++n) {
        const float g = c2r[n] - 2.f * acc[m][n][i];
        const float gm = g - M;
        const float e = __expf(-alpha * gm);
        se += e;
        sge += gm * e;
      }
#pragma unroll
      for (int msk = 1; msk < 16; msk <<= 1) {
        se += __shfl_xor(se, msk, 64);
        sge += __shfl_xor(sge, msk, 64);
      }
      if (l15 == 0) {
        redse[w * 128 + row] = se;
        redsge[w * 128 + row] = sge;
      }
    }
  }
  __syncthreads();
  if (t < 128) {
    float Se = 0.f, Sge = 0.f;
#pragma unroll
    for (int w2 = 0; w2 < 8; ++w2) {
      Se += redse[w2 * 128 + t];
      Sge += redsge[w2 * 128 + t];
    }
    float v = gmin[t] + Sge / Se + x2s[t];
#pragma unroll
    for (int msk = 1; msk < 64; msk <<= 1) v += __shfl_xor(v, msk, 64);
    if ((t & 63) == 0) redmin[t >> 6] = v;
  }
  __syncthreads();
  if (t == 0) partials[bid] = redmin[0] + redmin[1];
}

// ---------- final deterministic reduction ----------
__global__ __launch_bounds__(256) void final_kernel(const uint8_t* __restrict__ ws,
                                                    const float* __restrict__ lambdp,
                                                    float* __restrict__ out) {
  const float* partials = (const float*)(ws + WS_PART);
  const int t = threadIdx.x;
  float s = 0.f;
  for (int i = t; i < NBLK; i += 256) s += partials[i];
#pragma unroll
  for (int msk = 1; msk < 64; msk <<= 1) s += __shfl_xor(s, msk, 64);
  __shared__ float red[4];
  if ((t & 63) == 0) red[t >> 6] = s;
  __syncthreads();
  if (t == 0)
    out[0] = lambdp[0] * (red[0] + red[1] + red[2] + red[3]) * (1.0f / (float)NPTS);
}

extern "C" void kernel_launch(void* const* d_in, const int* in_sizes, int n_in,
                              void* d_out, int out_size, void* d_ws, size_t ws_size,
                              hipStream_t stream) {
  const float* emb = (const float*)d_in[0];
  const float* cent = (const float*)d_in[1];
  const float* alphap = (const float*)d_in[2];
  const float* lambdp = (const float*)d_in[3];
  float* out = (float*)d_out;
  uint8_t* ws = (uint8_t*)d_ws;

  prep_kernel<<<NCL, 128, 0, stream>>>(cent, ws);
  main_kernel<<<NBLK, NTHREADS, 0, stream>>>(emb, ws, alphap);
  final_kernel<<<1, 256, 0, stream>>>(ws, lambdp, out);
}

// Round 9
// 132.979 us; speedup vs baseline: 1.3574x; 1.3574x over previous
//
#include <hip/hip_runtime.h>
#include <stdint.h>

#define NPTS   131072
#define DEMB   512
#define NCL    512
#define BM     128
#define NCHUNK 8
#define NTHREADS 512
#define NBLK   (NPTS / BM)          // 1024

typedef __attribute__((ext_vector_type(4))) float f32x4;
typedef __attribute__((ext_vector_type(8))) short short8;

// ---- workspace layout (bytes) ----
// [0, 512KB)  : bf16 centroid fragments, per (chunk, wave, kk, n, lane):
//               each wave's (ch,kk,n) B-fragment is one contiguous 1KB wave-read.
// [512KB,+2KB): c2[k] = ||c_k||^2 (f32)
// [514KB,+8KB): per-block partial sums (f32)
#define WS_CB   0u
#define WS_C2   (512u * 1024u)
#define WS_PART (WS_C2 + 2048u)

static __device__ __forceinline__ unsigned short f2bf(float f) {
  union { float f; uint32_t u; } c{f};
  uint32_t r = c.u + 0x7FFFu + ((c.u >> 16) & 1u);   // round-to-nearest-even
  return (unsigned short)(r >> 16);
}

static __device__ __forceinline__ float sq4(f32x4 v) {
  return v[0] * v[0] + v[1] * v[1] + v[2] * v[2] + v[3] * v[3];
}
static __device__ __forceinline__ ushort4 cvt4(f32x4 v) {
  ushort4 u;
  u.x = f2bf(v[0]); u.y = f2bf(v[1]); u.z = f2bf(v[2]); u.w = f2bf(v[3]);
  return u;
}

// ---- pinned-schedule load/wait primitives (volatile asm keeps program order) ----
#define LOAD_B8(DST, BASE)                                                     \
  do {                                                                         \
    const uint8_t* _b0 = (const uint8_t*)(BASE);                               \
    const uint8_t* _b1 = _b0 + 4096;                                           \
    asm volatile("global_load_dwordx4 %0, %8, off\n\t"                         \
                 "global_load_dwordx4 %1, %8, off offset:1024\n\t"             \
                 "global_load_dwordx4 %2, %8, off offset:2048\n\t"             \
                 "global_load_dwordx4 %3, %8, off offset:3072\n\t"             \
                 "global_load_dwordx4 %4, %9, off\n\t"                         \
                 "global_load_dwordx4 %5, %9, off offset:1024\n\t"             \
                 "global_load_dwordx4 %6, %9, off offset:2048\n\t"             \
                 "global_load_dwordx4 %7, %9, off offset:3072"                 \
                 : "=&v"(DST[0]), "=&v"(DST[1]), "=&v"(DST[2]), "=&v"(DST[3]), \
                   "=&v"(DST[4]), "=&v"(DST[5]), "=&v"(DST[6]), "=&v"(DST[7])  \
                 : "v"(_b0), "v"(_b1)                                          \
                 : "memory");                                                  \
  } while (0)

#define LOAD_E4(D, P)                                                          \
  asm volatile("global_load_dwordx4 %0, %4, off\n\t"                           \
               "global_load_dwordx4 %1, %4, off offset:16\n\t"                 \
               "global_load_dwordx4 %2, %4, off offset:32\n\t"                 \
               "global_load_dwordx4 %3, %4, off offset:48"                     \
               : "=&v"(D[0]), "=&v"(D[1]), "=&v"(D[2]), "=&v"(D[3])            \
               : "v"(P)                                                        \
               : "memory")

#define WAITV(N)                                                               \
  do {                                                                         \
    asm volatile("s_waitcnt vmcnt(" #N ")" ::: "memory");                      \
    __builtin_amdgcn_sched_barrier(0);                                         \
  } while (0)

#define BAR()                                                                  \
  do {                                                                         \
    asm volatile("s_waitcnt lgkmcnt(0)" ::: "memory");                         \
    __builtin_amdgcn_s_barrier();                                              \
  } while (0)

// ---------- prep: c2 + bf16 centroid fragments in register-load layout ----------
__global__ __launch_bounds__(128) void prep_kernel(const float* __restrict__ cent,
                                                   uint8_t* __restrict__ ws) {
  const int k = blockIdx.x;
  const int t = threadIdx.x;
  float4 v = ((const float4*)(cent + (size_t)k * DEMB))[t];
  float sq = v.x * v.x + v.y * v.y + v.z * v.z + v.w * v.w;
#pragma unroll
  for (int m = 1; m < 64; m <<= 1) sq += __shfl_xor(sq, m, 64);
  __shared__ float red[2];
  if ((t & 63) == 0) red[t >> 6] = sq;
  __syncthreads();
  if (t == 0) ((float*)(ws + WS_C2))[k] = red[0] + red[1];

  ushort4 b;
  b.x = f2bf(v.x); b.y = f2bf(v.y); b.z = f2bf(v.z); b.w = f2bf(v.w);
  const int d = t * 4;
  const int ch = d >> 6;
  const int dd = d & 63;
  const int slot = dd >> 3;            // 0..7
  const int kk = slot >> 2;            // 0..1
  const int lhi = slot & 3;            // 0..3
  const int w = k >> 6;
  const int kc = k & 63;
  const int n = kc >> 4;
  const int l15 = kc & 15;
  const int lane = lhi * 16 + l15;
  const uint32_t off =
      ((((uint32_t)(ch * 8 + w) * 2u + (uint32_t)kk) * 4u + (uint32_t)n) * 64u +
       (uint32_t)lane) * 16u + (uint32_t)(dd & 7) * 2u;
  *(ushort4*)(ws + WS_CB + off) = b;
}

// ---------- fused GEMM + softmin epilogue: BM=128, depth-2 E, single wait/body ----------
__global__ __launch_bounds__(NTHREADS, 2) void main_kernel(
    const float* __restrict__ emb, const uint8_t* __restrict__ ws,
    const float* __restrict__ alphap) {
  __shared__ uint8_t Ab[2][16384];     // A tile dbuf [128 rows][64 d] bf16, XOR-swizzled
  __shared__ float redmin[1024];       // [8 waves][128 rows]
  __shared__ float redse[1024];
  __shared__ float redsge[1024];
  __shared__ float gmin[128];
  __shared__ float x2s[128];

  const int t = threadIdx.x;
  const int w = t >> 6;                // wave 0..7 -> clusters [64w, 64w+64)
  const int l = t & 63;
  const int l15 = l & 15;
  const int lhi = l >> 4;              // 0..3
  const int bid = blockIdx.x;
  const size_t row0 = (size_t)bid * BM;

  float* partials = (float*)(ws + WS_PART);

  f32x4 acc[8][4];
#pragma unroll
  for (int m = 0; m < 8; ++m)
#pragma unroll
    for (int n = 0; n < 4; ++n) acc[m][n] = (f32x4){0.f, 0.f, 0.f, 0.f};

  // x staging: thread owns 64B of one row: row r = t>>2, float cols [q*16, q*16+16)
  const int r = t >> 2;
  const int q = t & 3;
  const float* xge = emb + (row0 + r) * DEMB + q * 16;
  uint32_t xoffs[4];
#pragma unroll
  for (int j = 0; j < 4; ++j)
    xoffs[j] = (uint32_t)r * 128u +
               (uint32_t)((((2 * q + (j >> 1)) ^ (r & 7)) << 4) + (j & 1) * 8);

  float x2a = 0.f;

  // per-wave B fragment base: lane l's 16B; frag (ch,kk,n) at + ch*64KB + (kk*4+n)*1KB
  const uint8_t* fb = ws + WS_CB + (uint32_t)w * 8192u + (uint32_t)l * 16u;

  short8 bA[8], bB[8];
  f32x4 ev0[4], ev1[4];

#define STAGE_FROM(EV, DSTBUF)                                                 \
  do {                                                                         \
    uint8_t* _an = (DSTBUF);                                                   \
    _Pragma("unroll")                                                          \
    for (int j = 0; j < 4; ++j) {                                              \
      x2a += sq4(EV[j]);                                                       \
      *(ushort4*)(_an + xoffs[j]) = cvt4(EV[j]);                               \
    }                                                                          \
  } while (0)

  // ---- prologue: E[0]->ev0, E[1]->ev1, B[0]->bA; wait E[0] only; stage A[0] ----
  LOAD_E4(ev0, xge);
  LOAD_E4(ev1, xge + 64);
  LOAD_B8(bA, fb);
  WAITV(12);                           // retires E[0]; E[1]+B[0] stay in flight
  STAGE_FROM(ev0, &Ab[0][0]);
  BAR();

// Depth-2 E, single counted wait per body.
// Steady-state ledger at body ch top: E[ch+1](4) + B[ch](8) outstanding.
// Issue E[ch+2](4) + B[ch+1](8) -> 24; WAITV(12) retires E[ch+1]+B[ch]
// (B for this body's MFMAs, E for this body's staging -- no second wait).
//   bodies 0-5: WAITV(12); body 6 (no E issue): WAITV(8); body 7: WAITV(0).
// WAW safe: E[ch+2] targets ev[ch&1], whose prior load E[ch] was retired at
// body ch-1's WAITV and consumed before body ch-1's BAR.
#define CHUNK_BODY(CH, BCUR, BNEXT, EVN, EVS, VN)                              \
  {                                                                            \
    if ((CH) + 2 < NCHUNK)                                                     \
      LOAD_E4(EVN, xge + ((CH) + 2) * 64);                                     \
    if ((CH) + 1 < NCHUNK)                                                     \
      LOAD_B8(BNEXT, fb + (uint32_t)((CH) + 1) * 65536u);                      \
    const uint8_t* xb = &Ab[(CH) & 1][0];                                      \
    WAITV(VN);                                                                 \
    __builtin_amdgcn_s_setprio(1);                                             \
    _Pragma("unroll")                                                          \
    for (int kk = 0; kk < 2; ++kk) {                                           \
      const int slot = kk * 4 + lhi;                                           \
      const uint32_t fo =                                                      \
          (uint32_t)l15 * 128u + (uint32_t)((slot ^ (l15 & 7)) << 4);          \
      _Pragma("unroll")                                                        \
      for (int mh = 0; mh < 2; ++mh) {                                         \
        short8 af[4];                                                          \
        _Pragma("unroll")                                                      \
        for (int mm = 0; mm < 4; ++mm)                                         \
          af[mm] =                                                             \
              *(const short8*)(xb + fo + (uint32_t)(mh * 4 + mm) * 2048u);     \
        _Pragma("unroll")                                                      \
        for (int mm = 0; mm < 4; ++mm)                                         \
          _Pragma("unroll")                                                    \
          for (int n = 0; n < 4; ++n)                                          \
            acc[mh * 4 + mm][n] = __builtin_amdgcn_mfma_f32_16x16x32_bf16(     \
                af[mm], BCUR[kk * 4 + n], acc[mh * 4 + mm][n], 0, 0, 0);       \
      }                                                                        \
    }                                                                          \
    __builtin_amdgcn_s_setprio(0);                                             \
    if ((CH) + 1 < NCHUNK)                                                     \
      STAGE_FROM(EVS, &Ab[((CH) + 1) & 1][0]);                                 \
    BAR();                                                                     \
  }

  CHUNK_BODY(0, bA, bB, ev0, ev1, 12)
  CHUNK_BODY(1, bB, bA, ev1, ev0, 12)
  CHUNK_BODY(2, bA, bB, ev0, ev1, 12)
  CHUNK_BODY(3, bB, bA, ev1, ev0, 12)
  CHUNK_BODY(4, bA, bB, ev0, ev1, 12)
  CHUNK_BODY(5, bB, bA, ev1, ev0, 12)
  CHUNK_BODY(6, bA, bB, ev0, ev1, 8)
  CHUNK_BODY(7, bB, bA, ev1, ev0, 0)
#undef CHUNK_BODY
#undef STAGE_FROM

  // ---- epilogue: g = c2 - 2*s ; val_row = min + sum((g-M)e)/sum(e) + x2 ----
  const float alpha = alphap[0];
  float c2r[4];
  {
    const float* c2p = (const float*)(ws + WS_C2) + w * 64 + l15;
    asm volatile("global_load_dword %0, %4, off\n\t"
                 "global_load_dword %1, %4, off offset:64\n\t"
                 "global_load_dword %2, %4, off offset:128\n\t"
                 "global_load_dword %3, %4, off offset:192"
                 : "=&v"(c2r[0]), "=&v"(c2r[1]), "=&v"(c2r[2]), "=&v"(c2r[3])
                 : "v"(c2p)
                 : "memory");
    asm volatile("s_waitcnt vmcnt(0)" ::: "memory");
    __builtin_amdgcn_sched_barrier(0);
  }

  // per-row x2: 4 threads per row (lanes 4k..4k+3)
  x2a += __shfl_xor(x2a, 1, 64);
  x2a += __shfl_xor(x2a, 2, 64);
  if ((l & 3) == 0) x2s[r] = x2a;     // one writer per row

  float rmin[8][4];
#pragma unroll
  for (int m = 0; m < 8; ++m)
#pragma unroll
    for (int i = 0; i < 4; ++i) {
      float mn = c2r[0] - 2.f * acc[m][0][i];
#pragma unroll
      for (int n = 1; n < 4; ++n) mn = fminf(mn, c2r[n] - 2.f * acc[m][n][i]);
      rmin[m][i] = mn;
    }
#pragma unroll
  for (int msk = 1; msk < 16; msk <<= 1)
#pragma unroll
    for (int m = 0; m < 8; ++m)
#pragma unroll
      for (int i = 0; i < 4; ++i)
        rmin[m][i] = fminf(rmin[m][i], __shfl_xor(rmin[m][i], msk, 64));
  if (l15 == 0) {
#pragma unroll
    for (int m = 0; m < 8; ++m)
#pragma unroll
      for (int i = 0; i < 4; ++i)
        redmin[w * 128 + m * 16 + lhi * 4 + i] = rmin[m][i];
  }
  __syncthreads();
  if (t < 128) {
    float mn = redmin[t];
#pragma unroll
    for (int w2 = 1; w2 < 8; ++w2) mn = fminf(mn, redmin[w2 * 128 + t]);
    gmin[t] = mn;
  }
  __syncthreads();
#pragma unroll
  for (int m = 0; m < 8; ++m) {
#pragma unroll
    for (int i = 0; i < 4; ++i) {
      const int row = m * 16 + lhi * 4 + i;
      const float M = gmin[row];
      float se = 0.f, sge = 0.f;
#pragma unroll
      for (int n = 0; n < 4; ++n) {
        const float g = c2r[n] - 2.f * acc[m][n][i];
        const float gm = g - M;
        const float e = __expf(-alpha * gm);
        se += e;
        sge += gm * e;
      }
#pragma unroll
      for (int msk = 1; msk < 16; msk <<= 1) {
        se += __shfl_xor(se, msk, 64);
        sge += __shfl_xor(sge, msk, 64);
      }
      if (l15 == 0) {
        redse[w * 128 + row] = se;
        redsge[w * 128 + row] = sge;
      }
    }
  }
  __syncthreads();
  if (t < 128) {
    float Se = 0.f, Sge = 0.f;
#pragma unroll
    for (int w2 = 0; w2 < 8; ++w2) {
      Se += redse[w2 * 128 + t];
      Sge += redsge[w2 * 128 + t];
    }
    float v = gmin[t] + Sge / Se + x2s[t];
#pragma unroll
    for (int msk = 1; msk < 64; msk <<= 1) v += __shfl_xor(v, msk, 64);
    if ((t & 63) == 0) redmin[t >> 6] = v;
  }
  __syncthreads();
  if (t == 0) partials[bid] = redmin[0] + redmin[1];
}

// ---------- final deterministic reduction ----------
__global__ __launch_bounds__(256) void final_kernel(const uint8_t* __restrict__ ws,
                                                    const float* __restrict__ lambdp,
                                                    float* __restrict__ out) {
  const float* partials = (const float*)(ws + WS_PART);
  const int t = threadIdx.x;
  float s = 0.f;
  for (int i = t; i < NBLK; i += 256) s += partials[i];
#pragma unroll
  for (int msk = 1; msk < 64; msk <<= 1) s += __shfl_xor(s, msk, 64);
  __shared__ float red[4];
  if ((t & 63) == 0) red[t >> 6] = s;
  __syncthreads();
  if (t == 0)
    out[0] = lambdp[0] * (red[0] + red[1] + red[2] + red[3]) * (1.0f / (float)NPTS);
}

extern "C" void kernel_launch(void* const* d_in, const int* in_sizes, int n_in,
                              void* d_out, int out_size, void* d_ws, size_t ws_size,
                              hipStream_t stream) {
  const float* emb = (const float*)d_in[0];
  const float* cent = (const float*)d_in[1];
  const float* alphap = (const float*)d_in[2];
  const float* lambdp = (const float*)d_in[3];
  float* out = (float*)d_out;
  uint8_t* ws = (uint8_t*)d_ws;

  prep_kernel<<<NCL, 128, 0, stream>>>(cent, ws);
  main_kernel<<<NBLK, NTHREADS, 0, stream>>>(emb, ws, alphap);
  final_kernel<<<1, 256, 0, stream>>>(ws, lambdp, out);
}